// Round 1
// baseline (295.084 us; speedup 1.0000x reference)
//
#include <hip/hip_runtime.h>

#define N_NODES 50000
#define N_EDGES 800000
#define D 64

// ---------------------------------------------------------------------------
// K1: init degrees to 1 (accounts for the self-edge in the reference concat)
// ---------------------------------------------------------------------------
__global__ void init_deg_kernel(int* __restrict__ sdeg, int* __restrict__ rdeg) {
    int i = blockIdx.x * blockDim.x + threadIdx.x;
    if (i < N_NODES) { sdeg[i] = 1; rdeg[i] = 1; }
}

// ---------------------------------------------------------------------------
// K2: count sender/receiver degrees over the 800k edges
// ---------------------------------------------------------------------------
__global__ void count_deg_kernel(const int* __restrict__ s, const int* __restrict__ r,
                                 int* __restrict__ sdeg, int* __restrict__ rdeg) {
    int e = blockIdx.x * blockDim.x + threadIdx.x;
    if (e < N_EDGES) {
        atomicAdd(&sdeg[s[e]], 1);
        atomicAdd(&rdeg[r[e]], 1);
    }
}

// ---------------------------------------------------------------------------
// K3: h = (x @ W^T + b) * rsqrt(sender_deg);  out = h  (self-edge contribution)
// One wave handles one node-row at a time: lane = output channel o,
// W row 'o' lives in 16 float4 registers, x row broadcast via float4 loads.
// ---------------------------------------------------------------------------
__global__ __launch_bounds__(256) void linear_kernel(
        const float* __restrict__ x, const float* __restrict__ w,
        const float* __restrict__ bias, const int* __restrict__ sdeg,
        float* __restrict__ h, float* __restrict__ out) {
    const int lane = threadIdx.x & 63;
    const int wid = blockIdx.x * (blockDim.x >> 6) + (threadIdx.x >> 6);
    const int nwaves = gridDim.x * (blockDim.x >> 6);

    // W[o][k] row for o = lane, 64 floats = 16 float4 regs
    float4 wreg[16];
    #pragma unroll
    for (int i = 0; i < 16; ++i) wreg[i] = ((const float4*)w)[lane * 16 + i];
    const float bo = bias[lane];

    for (int n = wid; n < N_NODES; n += nwaves) {
        const float4* xr = (const float4*)(x + n * D);
        float acc = bo;
        #pragma unroll
        for (int i = 0; i < 16; ++i) {
            float4 xv = xr[i];  // wave-uniform broadcast
            acc += xv.x * wreg[i].x + xv.y * wreg[i].y
                 + xv.z * wreg[i].z + xv.w * wreg[i].w;
        }
        float v = acc * rsqrtf((float)sdeg[n]);
        h[n * D + lane]   = v;
        out[n * D + lane] = v;  // self-edge term
    }
}

// ---------------------------------------------------------------------------
// K4: scatter-add h[sender] into out[receiver]. One wave per edge, lane = d.
// ---------------------------------------------------------------------------
__global__ __launch_bounds__(256) void scatter_kernel(
        const int* __restrict__ s, const int* __restrict__ r,
        const float* __restrict__ h, float* __restrict__ out) {
    long long gid = (long long)blockIdx.x * blockDim.x + threadIdx.x;
    int e = (int)(gid >> 6);
    int d = (int)(gid & 63);
    if (e >= N_EDGES) return;
    int se = s[e];  // wave-uniform
    int re = r[e];  // wave-uniform
    atomicAdd(&out[re * D + d], h[se * D + d]);
}

// ---------------------------------------------------------------------------
// K5: out = leaky_relu(out * rsqrt(receiver_deg))
// ---------------------------------------------------------------------------
__global__ __launch_bounds__(256) void finalize_kernel(
        const int* __restrict__ rdeg, float* __restrict__ out) {
    int gid = blockIdx.x * blockDim.x + threadIdx.x;
    if (gid >= N_NODES * D) return;
    float sc = rsqrtf((float)rdeg[gid >> 6]);
    float v = out[gid] * sc;
    out[gid] = v > 0.0f ? v : 0.01f * v;
}

// ---------------------------------------------------------------------------
extern "C" void kernel_launch(void* const* d_in, const int* in_sizes, int n_in,
                              void* d_out, int out_size, void* d_ws, size_t ws_size,
                              hipStream_t stream) {
    const float* x       = (const float*)d_in[0];
    const int*   senders = (const int*)d_in[1];
    const int*   recvs   = (const int*)d_in[2];
    const float* weight  = (const float*)d_in[3];
    const float* bias    = (const float*)d_in[4];
    float* out = (float*)d_out;

    // workspace layout
    float* h   = (float*)d_ws;                                   // 12.8 MB
    int*   sdeg = (int*)((char*)d_ws + (size_t)N_NODES * D * 4); // 200 KB
    int*   rdeg = sdeg + N_NODES;                                // 200 KB

    hipLaunchKernelGGL(init_deg_kernel, dim3((N_NODES + 255) / 256), dim3(256), 0, stream,
                       sdeg, rdeg);
    hipLaunchKernelGGL(count_deg_kernel, dim3((N_EDGES + 255) / 256), dim3(256), 0, stream,
                       senders, recvs, sdeg, rdeg);
    hipLaunchKernelGGL(linear_kernel, dim3(1024), dim3(256), 0, stream,
                       x, weight, bias, sdeg, h, out);
    {
        long long total = (long long)N_EDGES * 64;
        int blocks = (int)((total + 255) / 256);
        hipLaunchKernelGGL(scatter_kernel, dim3(blocks), dim3(256), 0, stream,
                           senders, recvs, h, out);
    }
    hipLaunchKernelGGL(finalize_kernel, dim3((N_NODES * D + 255) / 256), dim3(256), 0, stream,
                       rdeg, out);
}

// Round 2
// 228.918 us; speedup vs baseline: 1.2890x; 1.2890x over previous
//
#include <hip/hip_runtime.h>

#define N_NODES 50000
#define N_EDGES 800000
#define D 64
#define NBLK 196  // ceil(50000/256)

// ---------------------------------------------------------------------------
// K1: init degrees to 1 (self-edge folded in)
// ---------------------------------------------------------------------------
__global__ void init_deg_kernel(int* __restrict__ sdeg, int* __restrict__ rdeg) {
    int i = blockIdx.x * blockDim.x + threadIdx.x;
    if (i < N_NODES) { sdeg[i] = 1; rdeg[i] = 1; }
}

// ---------------------------------------------------------------------------
// K2: count sender/receiver degrees (int atomics, low contention)
// ---------------------------------------------------------------------------
__global__ void count_deg_kernel(const int* __restrict__ s, const int* __restrict__ r,
                                 int* __restrict__ sdeg, int* __restrict__ rdeg) {
    int e = blockIdx.x * blockDim.x + threadIdx.x;
    if (e < N_EDGES) {
        atomicAdd(&sdeg[s[e]], 1);
        atomicAdd(&rdeg[r[e]], 1);
    }
}

// ---------------------------------------------------------------------------
// K3: h = (x @ W^T + b) * rsqrt(sender_deg)
// ---------------------------------------------------------------------------
__global__ __launch_bounds__(256) void linear_kernel(
        const float* __restrict__ x, const float* __restrict__ w,
        const float* __restrict__ bias, const int* __restrict__ sdeg,
        float* __restrict__ h) {
    const int lane = threadIdx.x & 63;
    const int wid = blockIdx.x * (blockDim.x >> 6) + (threadIdx.x >> 6);
    const int nwaves = gridDim.x * (blockDim.x >> 6);

    float4 wreg[16];
    #pragma unroll
    for (int i = 0; i < 16; ++i) wreg[i] = ((const float4*)w)[lane * 16 + i];
    const float bo = bias[lane];

    for (int n = wid; n < N_NODES; n += nwaves) {
        const float4* xr = (const float4*)(x + n * D);
        float acc = bo;
        #pragma unroll
        for (int i = 0; i < 16; ++i) {
            float4 xv = xr[i];
            acc += xv.x * wreg[i].x + xv.y * wreg[i].y
                 + xv.z * wreg[i].z + xv.w * wreg[i].w;
        }
        h[n * D + lane] = acc * rsqrtf((float)sdeg[n]);
    }
}

// ---------------------------------------------------------------------------
// Scan step 1: per-block sums of real receiver degree (rdeg-1)
// ---------------------------------------------------------------------------
__global__ __launch_bounds__(256) void scan1_kernel(const int* __restrict__ rdeg,
                                                    int* __restrict__ bsum) {
    int i = blockIdx.x * 256 + threadIdx.x;
    int v = (i < N_NODES) ? rdeg[i] - 1 : 0;
    #pragma unroll
    for (int o = 32; o > 0; o >>= 1) v += __shfl_down(v, o);
    __shared__ int ws[4];
    if ((threadIdx.x & 63) == 0) ws[threadIdx.x >> 6] = v;
    __syncthreads();
    if (threadIdx.x == 0) bsum[blockIdx.x] = ws[0] + ws[1] + ws[2] + ws[3];
}

// ---------------------------------------------------------------------------
// Scan step 2: exclusive scan of the NBLK block sums (single block)
// ---------------------------------------------------------------------------
__global__ __launch_bounds__(256) void scan2_kernel(int* __restrict__ bsum) {
    int t = threadIdx.x;
    int v = (t < NBLK) ? bsum[t] : 0;
    int lane = t & 63, w = t >> 6;
    int sv = v;
    #pragma unroll
    for (int o = 1; o < 64; o <<= 1) {
        int u = __shfl_up(sv, o);
        if (lane >= o) sv += u;
    }
    __shared__ int wsum[4];
    if (lane == 63) wsum[w] = sv;
    __syncthreads();
    int add = 0;
    for (int k = 0; k < w; ++k) add += wsum[k];
    int excl = sv + add - v;
    if (t < NBLK) bsum[t] = excl;
}

// ---------------------------------------------------------------------------
// Scan step 3: per-node exclusive offsets; also seed the fill cursors
// ---------------------------------------------------------------------------
__global__ __launch_bounds__(256) void scan3_kernel(
        const int* __restrict__ rdeg, const int* __restrict__ boff,
        int* __restrict__ rowoff, int* __restrict__ cursor) {
    int i = blockIdx.x * 256 + threadIdx.x;
    int v = (i < N_NODES) ? rdeg[i] - 1 : 0;
    int lane = threadIdx.x & 63, w = threadIdx.x >> 6;
    int sv = v;
    #pragma unroll
    for (int o = 1; o < 64; o <<= 1) {
        int u = __shfl_up(sv, o);
        if (lane >= o) sv += u;
    }
    __shared__ int wsum[4];
    if (lane == 63) wsum[w] = sv;
    __syncthreads();
    int add = boff[blockIdx.x];
    for (int k = 0; k < w; ++k) add += wsum[k];
    int excl = add + sv - v;
    if (i < N_NODES) { rowoff[i] = excl; cursor[i] = excl; }
}

// ---------------------------------------------------------------------------
// K4: counting-sort fill — bucket senders by receiver
// ---------------------------------------------------------------------------
__global__ void fill_kernel(const int* __restrict__ s, const int* __restrict__ r,
                            int* __restrict__ cursor, int* __restrict__ csr_s) {
    int e = blockIdx.x * blockDim.x + threadIdx.x;
    if (e < N_EDGES) {
        int pos = atomicAdd(&cursor[r[e]], 1);
        csr_s[pos] = s[e];
    }
}

// ---------------------------------------------------------------------------
// K5: gather-accumulate per receiver node + receiver rsqrt + leaky-relu
// One wave per node, lane = output channel.
// ---------------------------------------------------------------------------
__global__ __launch_bounds__(256) void gather_kernel(
        const float* __restrict__ h, const int* __restrict__ rowoff,
        const int* __restrict__ rdeg, const int* __restrict__ csr_s,
        float* __restrict__ out) {
    const int lane = threadIdx.x & 63;
    const int n = blockIdx.x * (blockDim.x >> 6) + (threadIdx.x >> 6);
    if (n >= N_NODES) return;

    float acc = h[n * D + lane];            // self-edge contribution
    const int base = rowoff[n];
    const int cnt = rdeg[n] - 1;

    for (int j0 = 0; j0 < cnt; j0 += 64) {
        int m = cnt - j0; if (m > 64) m = 64;
        int my = (lane < m) ? csr_s[base + j0 + lane] : 0;
        for (int t = 0; t < m; ++t) {
            int sidx = __shfl(my, t);       // wave-uniform sender index
            acc += h[sidx * D + lane];
        }
    }
    float v = acc * rsqrtf((float)rdeg[n]);
    out[n * D + lane] = v > 0.0f ? v : 0.01f * v;
}

// ---------------------------------------------------------------------------
extern "C" void kernel_launch(void* const* d_in, const int* in_sizes, int n_in,
                              void* d_out, int out_size, void* d_ws, size_t ws_size,
                              hipStream_t stream) {
    const float* x       = (const float*)d_in[0];
    const int*   senders = (const int*)d_in[1];
    const int*   recvs   = (const int*)d_in[2];
    const float* weight  = (const float*)d_in[3];
    const float* bias    = (const float*)d_in[4];
    float* out = (float*)d_out;

    // workspace layout (all 256B-aligned chunks)
    char* p = (char*)d_ws;
    float* h      = (float*)p;                 p += (size_t)N_NODES * D * 4;  // 12.8 MB
    int*   sdeg   = (int*)p;                   p += (size_t)N_NODES * 4;
    int*   rdeg   = (int*)p;                   p += (size_t)N_NODES * 4;
    int*   rowoff = (int*)p;                   p += (size_t)N_NODES * 4;
    int*   cursor = (int*)p;                   p += (size_t)N_NODES * 4;
    int*   bsum   = (int*)p;                   p += 1024;
    int*   csr_s  = (int*)p;                   // 3.2 MB

    hipLaunchKernelGGL(init_deg_kernel, dim3((N_NODES + 255) / 256), dim3(256), 0, stream,
                       sdeg, rdeg);
    hipLaunchKernelGGL(count_deg_kernel, dim3((N_EDGES + 255) / 256), dim3(256), 0, stream,
                       senders, recvs, sdeg, rdeg);
    hipLaunchKernelGGL(linear_kernel, dim3(1024), dim3(256), 0, stream,
                       x, weight, bias, sdeg, h);
    hipLaunchKernelGGL(scan1_kernel, dim3(NBLK), dim3(256), 0, stream, rdeg, bsum);
    hipLaunchKernelGGL(scan2_kernel, dim3(1), dim3(256), 0, stream, bsum);
    hipLaunchKernelGGL(scan3_kernel, dim3(NBLK), dim3(256), 0, stream,
                       rdeg, bsum, rowoff, cursor);
    hipLaunchKernelGGL(fill_kernel, dim3((N_EDGES + 255) / 256), dim3(256), 0, stream,
                       senders, recvs, cursor, csr_s);
    hipLaunchKernelGGL(gather_kernel, dim3((N_NODES * 64 + 255) / 256), dim3(256), 0, stream,
                       h, rowoff, rdeg, csr_s, out);
}